// Round 1
// baseline (255.404 us; speedup 1.0000x reference)
//
#include <hip/hip_runtime.h>

// Flash attention forward, fp32 in/out, fp16 MFMA compute.
// B=8, SQ=SK=4096, D=64. scores = (Q/ x5) K^T ; softmax ; O = P V.
// Block: 256 threads = 4 waves; each wave owns 32 Q rows (2 M-tiles of 16).
// BQ=128 -> grid = 8 * 32 = 256 blocks (1 per CU). BK=64 keys per iteration.

typedef _Float16 f16x8 __attribute__((ext_vector_type(8)));
typedef float    f32x4 __attribute__((ext_vector_type(4)));

constexpr int kB  = 8;
constexpr int kSQ = 4096;
constexpr int kSK = 4096;
constexpr int kD  = 64;
constexpr int BQ  = 128;
constexpr int BK  = 64;
constexpr int MT  = 2;          // M-tiles (16 rows) per wave
constexpr int LDK = kD + 8;     // 72: pad -> row stride 144 B (2-way bank alias, free)
constexpr int LDV = BK + 8;     // 72
constexpr int LDP = BK + 8;     // 72

__global__ __launch_bounds__(256, 1)
void fattn_kernel(const float* __restrict__ Qg,
                  const float* __restrict__ Kg,
                  const float* __restrict__ Vg,
                  const float* __restrict__ sdiv,
                  float* __restrict__ Og)
{
    __shared__ __align__(16) _Float16 sK[BK][LDK];        // [key][feat]
    __shared__ __align__(16) _Float16 sV[kD][LDV];        // [feat][key] (V transposed)
    __shared__ __align__(16) _Float16 sP[4][MT * 16][LDP]; // per-wave P buffer

    const int tid  = threadIdx.x;
    const int w    = tid >> 6;
    const int lane = tid & 63;
    const int l16  = lane & 15;
    const int quad = lane >> 4;

    const int b  = blockIdx.y;
    const int qb = blockIdx.x * BQ;

    const float inv_scale = 1.0f / sdiv[0];

    const float* Qb = Qg + ((size_t)b * kSQ + qb) * kD;
    const float* Kb = Kg + (size_t)b * kSK * kD;
    const float* Vb = Vg + (size_t)b * kSK * kD;

    // ---- Q fragments, held in registers for the whole kernel ----
    // A-layout: m = l16 (row within M-tile), k = ks*32 + quad*8 + j
    f16x8 qf[MT][2];
#pragma unroll
    for (int mt = 0; mt < MT; ++mt) {
        const float* qrow = Qb + (size_t)(w * 32 + mt * 16 + l16) * kD;
#pragma unroll
        for (int ks = 0; ks < 2; ++ks) {
            const float4 a = *(const float4*)(qrow + ks * 32 + quad * 8);
            const float4 c = *(const float4*)(qrow + ks * 32 + quad * 8 + 4);
            f16x8 f;
            f[0] = (_Float16)(a.x * inv_scale);
            f[1] = (_Float16)(a.y * inv_scale);
            f[2] = (_Float16)(a.z * inv_scale);
            f[3] = (_Float16)(a.w * inv_scale);
            f[4] = (_Float16)(c.x * inv_scale);
            f[5] = (_Float16)(c.y * inv_scale);
            f[6] = (_Float16)(c.z * inv_scale);
            f[7] = (_Float16)(c.w * inv_scale);
            qf[mt][ks] = f;
        }
    }

    // ---- online-softmax state ----
    f32x4 o[MT][4];                 // O accumulator, C-layout, 4 d-tiles of 16
    float m_i[MT][4], l_i[MT][4];
#pragma unroll
    for (int mt = 0; mt < MT; ++mt) {
#pragma unroll
        for (int r = 0; r < 4; ++r) { m_i[mt][r] = -1e30f; l_i[mt][r] = 0.0f; }
#pragma unroll
        for (int dt = 0; dt < 4; ++dt)
#pragma unroll
            for (int r = 0; r < 4; ++r) o[mt][dt][r] = 0.0f;
    }

    const int nIter = kSK / BK;
    for (int kt = 0; kt < nIter; ++kt) {
        __syncthreads();
        // ---- stage K tile and V tile (transposed) into LDS, fp32 -> fp16 ----
        const float* Kt = Kb + (size_t)kt * BK * kD;
        const float* Vt = Vb + (size_t)kt * BK * kD;
#pragma unroll
        for (int i = 0; i < 4; ++i) {
            const int idx = i * 256 + tid;
            const int row = idx >> 4;          // key row 0..63
            const int cb  = (idx & 15) * 4;    // feature col 0..60
            const float4 kv = *(const float4*)(Kt + row * kD + cb);
            _Float16* kd = &sK[row][cb];
            kd[0] = (_Float16)kv.x; kd[1] = (_Float16)kv.y;
            kd[2] = (_Float16)kv.z; kd[3] = (_Float16)kv.w;
            const float4 vv = *(const float4*)(Vt + row * kD + cb);
            sV[cb + 0][row] = (_Float16)vv.x;
            sV[cb + 1][row] = (_Float16)vv.y;
            sV[cb + 2][row] = (_Float16)vv.z;
            sV[cb + 3][row] = (_Float16)vv.w;
        }
        __syncthreads();

        // ---- S = Q K^T  (per wave: 32 rows x 64 keys) ----
        // B-layout for K: n = key = l16 (+nt*16), k = feature = ks*32 + quad*8 + j
        f16x8 kf[4][2];
#pragma unroll
        for (int nt = 0; nt < 4; ++nt)
#pragma unroll
            for (int ks = 0; ks < 2; ++ks)
                kf[nt][ks] = *(const f16x8*)&sK[nt * 16 + l16][ks * 32 + quad * 8];

        f32x4 s[MT][4];
#pragma unroll
        for (int mt = 0; mt < MT; ++mt)
#pragma unroll
            for (int nt = 0; nt < 4; ++nt) {
                f32x4 acc;
#pragma unroll
                for (int r = 0; r < 4; ++r) acc[r] = 0.0f;
                acc = __builtin_amdgcn_mfma_f32_16x16x32_f16(qf[mt][0], kf[nt][0], acc, 0, 0, 0);
                acc = __builtin_amdgcn_mfma_f32_16x16x32_f16(qf[mt][1], kf[nt][1], acc, 0, 0, 0);
                s[mt][nt] = acc;
            }

        // ---- online softmax (C-layout: col = l16 within tile, row = quad*4 + r) ----
#pragma unroll
        for (int mt = 0; mt < MT; ++mt) {
            float rm[4], rs[4], alpha[4];
#pragma unroll
            for (int r = 0; r < 4; ++r) {
                float v = s[mt][0][r];
                v = fmaxf(v, s[mt][1][r]);
                v = fmaxf(v, s[mt][2][r]);
                v = fmaxf(v, s[mt][3][r]);
                rm[r] = v;
            }
#pragma unroll
            for (int off = 1; off < 16; off <<= 1)
#pragma unroll
                for (int r = 0; r < 4; ++r)
                    rm[r] = fmaxf(rm[r], __shfl_xor(rm[r], off, 64));
#pragma unroll
            for (int r = 0; r < 4; ++r) {
                const float mnew = fmaxf(m_i[mt][r], rm[r]);
                alpha[r]  = __expf(m_i[mt][r] - mnew);
                m_i[mt][r] = mnew;
            }
#pragma unroll
            for (int r = 0; r < 4; ++r) {
                float sum = 0.0f;
#pragma unroll
                for (int nt = 0; nt < 4; ++nt) {
                    const float p = __expf(s[mt][nt][r] - m_i[mt][r]);
                    s[mt][nt][r] = p;
                    sum += p;
                }
                rs[r] = sum;
            }
#pragma unroll
            for (int off = 1; off < 16; off <<= 1)
#pragma unroll
                for (int r = 0; r < 4; ++r)
                    rs[r] += __shfl_xor(rs[r], off, 64);
#pragma unroll
            for (int r = 0; r < 4; ++r)
                l_i[mt][r] = l_i[mt][r] * alpha[r] + rs[r];
#pragma unroll
            for (int dt = 0; dt < 4; ++dt)
#pragma unroll
                for (int r = 0; r < 4; ++r)
                    o[mt][dt][r] *= alpha[r];
            // P: C-layout -> LDS (wave-private, no barrier needed)
#pragma unroll
            for (int nt = 0; nt < 4; ++nt)
#pragma unroll
                for (int r = 0; r < 4; ++r)
                    sP[w][mt * 16 + quad * 4 + r][nt * 16 + l16] = (_Float16)s[mt][nt][r];
        }

        // ---- O += P V ----
        // B-layout for V: n = feature = l16 (+dt*16), k = key = ks*32 + quad*8 + j
        f16x8 vf[4][2];
#pragma unroll
        for (int dt = 0; dt < 4; ++dt)
#pragma unroll
            for (int ks = 0; ks < 2; ++ks)
                vf[dt][ks] = *(const f16x8*)&sV[dt * 16 + l16][ks * 32 + quad * 8];
        f16x8 pf[MT][2];
#pragma unroll
        for (int mt = 0; mt < MT; ++mt)
#pragma unroll
            for (int ks = 0; ks < 2; ++ks)
                pf[mt][ks] = *(const f16x8*)&sP[w][mt * 16 + l16][ks * 32 + quad * 8];
#pragma unroll
        for (int mt = 0; mt < MT; ++mt)
#pragma unroll
            for (int dt = 0; dt < 4; ++dt) {
                o[mt][dt] = __builtin_amdgcn_mfma_f32_16x16x32_f16(pf[mt][0], vf[dt][0], o[mt][dt], 0, 0, 0);
                o[mt][dt] = __builtin_amdgcn_mfma_f32_16x16x32_f16(pf[mt][1], vf[dt][1], o[mt][dt], 0, 0, 0);
            }
    }

    // ---- epilogue: normalize by l and store fp32 ----
    float* Ob = Og + ((size_t)b * kSQ + qb) * kD;
#pragma unroll
    for (int mt = 0; mt < MT; ++mt)
#pragma unroll
        for (int r = 0; r < 4; ++r) {
            const float linv = 1.0f / l_i[mt][r];
            const int row = w * 32 + mt * 16 + quad * 4 + r;
#pragma unroll
            for (int dt = 0; dt < 4; ++dt)
                Ob[(size_t)row * kD + dt * 16 + l16] = o[mt][dt][r] * linv;
        }
}

extern "C" void kernel_launch(void* const* d_in, const int* in_sizes, int n_in,
                              void* d_out, int out_size, void* d_ws, size_t ws_size,
                              hipStream_t stream) {
    const float* Q    = (const float*)d_in[0];
    const float* K    = (const float*)d_in[1];
    const float* V    = (const float*)d_in[2];
    // d_in[3] = dropout p (static 0) -> unused
    const float* sdiv = (const float*)d_in[4];
    float* O = (float*)d_out;

    dim3 grid(kSQ / BQ, kB);
    fattn_kernel<<<grid, dim3(256), 0, stream>>>(Q, K, V, sdiv, O);
}